// Round 2
// baseline (79.207 us; speedup 1.0000x reference)
//
#include <hip/hip_runtime.h>

constexpr int C  = 21;
constexpr int CC = C * C;   // 441 bins per batch
constexpr int NSUB = 4;     // one sub-histogram per wave (256 threads = 4 waves)

// ---------- stage A: per-block partial histograms (no global atomics) ----------
__global__ __launch_bounds__(256)
void conf_hist_partial(const int* __restrict__ yp,
                       const int* __restrict__ y,
                       unsigned int* __restrict__ partial,   // [gridDim.x][CC]
                       int n_per_batch,
                       int blocks_per_batch) {
    __shared__ unsigned int hist[NSUB][CC];

    const int tid = threadIdx.x;
    for (int i = tid; i < NSUB * CC; i += 256)
        ((unsigned int*)hist)[i] = 0u;
    __syncthreads();

    const int b   = blockIdx.x / blocks_per_batch;
    const int blk = blockIdx.x % blocks_per_batch;

    const int4* yp4 = (const int4*)(yp + (size_t)b * n_per_batch);
    const int4* y4  = (const int4*)(y  + (size_t)b * n_per_batch);
    const int n4 = n_per_batch >> 2;
    const int stride = blocks_per_batch * 256;

    unsigned int* h = hist[tid >> 6];

    // unroll x2: keep two int4 pairs in flight before the DS atomics
    for (int i0 = blk * 256 + tid; i0 < n4; i0 += 2 * stride) {
        const int i1 = i0 + stride;
        int4 a0 = yp4[i0];
        int4 c0 = y4[i0];
        int4 a1, c1;
        const bool has1 = (i1 < n4);
        if (has1) { a1 = yp4[i1]; c1 = y4[i1]; }

        atomicAdd(&h[a0.x * C + c0.x], 1u);
        atomicAdd(&h[a0.y * C + c0.y], 1u);
        atomicAdd(&h[a0.z * C + c0.z], 1u);
        atomicAdd(&h[a0.w * C + c0.w], 1u);
        if (has1) {
            atomicAdd(&h[a1.x * C + c1.x], 1u);
            atomicAdd(&h[a1.y * C + c1.y], 1u);
            atomicAdd(&h[a1.z * C + c1.z], 1u);
            atomicAdd(&h[a1.w * C + c1.w], 1u);
        }
    }
    __syncthreads();

    // each block owns its partial slice — plain coalesced stores
    unsigned int* pb = partial + (size_t)blockIdx.x * CC;
    for (int i = tid; i < CC; i += 256)
        pb[i] = hist[0][i] + hist[1][i] + hist[2][i] + hist[3][i];
}

// ---------- stage B: sum partials, fully overwrite out ----------
__global__ __launch_bounds__(512)
void conf_reduce(const unsigned int* __restrict__ partial,
                 float* __restrict__ out,
                 int blocks_per_batch) {
    const int b = blockIdx.x;       // one block per batch
    const int i = threadIdx.x;
    if (i < CC) {
        const unsigned int* p = partial + (size_t)b * blocks_per_batch * CC + i;
        unsigned int s = 0;
        for (int k = 0; k < blocks_per_batch; ++k)
            s += p[(size_t)k * CC];
        out[(size_t)b * CC + i] = (float)s;
    }
}

// ---------- fallback path (small ws): global-atomic merge ----------
__global__ void zero_out_kernel(float* __restrict__ out, int n) {
    int i = blockIdx.x * blockDim.x + threadIdx.x;
    if (i < n) out[i] = 0.0f;
}

__global__ __launch_bounds__(256)
void conf_hist_atomic(const int* __restrict__ yp,
                      const int* __restrict__ y,
                      float* __restrict__ out,
                      int n_per_batch,
                      int blocks_per_batch) {
    __shared__ unsigned int hist[NSUB][CC];
    const int tid = threadIdx.x;
    for (int i = tid; i < NSUB * CC; i += 256)
        ((unsigned int*)hist)[i] = 0u;
    __syncthreads();

    const int b   = blockIdx.x / blocks_per_batch;
    const int blk = blockIdx.x % blocks_per_batch;
    const int4* yp4 = (const int4*)(yp + (size_t)b * n_per_batch);
    const int4* y4  = (const int4*)(y  + (size_t)b * n_per_batch);
    const int n4 = n_per_batch >> 2;
    unsigned int* h = hist[tid >> 6];

    for (int i = blk * 256 + tid; i < n4; i += blocks_per_batch * 256) {
        int4 a = yp4[i];
        int4 c = y4[i];
        atomicAdd(&h[a.x * C + c.x], 1u);
        atomicAdd(&h[a.y * C + c.y], 1u);
        atomicAdd(&h[a.z * C + c.z], 1u);
        atomicAdd(&h[a.w * C + c.w], 1u);
    }
    __syncthreads();

    float* ob = out + (size_t)b * CC;
    for (int i = tid; i < CC; i += 256) {
        unsigned int s = hist[0][i] + hist[1][i] + hist[2][i] + hist[3][i];
        if (s) atomicAdd(&ob[i], (float)s);
    }
}

extern "C" void kernel_launch(void* const* d_in, const int* in_sizes, int n_in,
                              void* d_out, int out_size, void* d_ws, size_t ws_size,
                              hipStream_t stream) {
    const int* yp = (const int*)d_in[0];
    const int* y  = (const int*)d_in[1];
    float* out    = (float*)d_out;

    const int total = in_sizes[0];          // B*H*W = 33,554,432
    const int B = out_size / CC;            // 8
    const int n_per_batch = total / B;      // 4,194,304

    const int blocks_per_batch = 256;       // 2048 blocks total, 8/CU
    const int nblocks = B * blocks_per_batch;
    const size_t ws_needed = (size_t)nblocks * CC * sizeof(unsigned int); // ~3.6 MB

    if (ws_size >= ws_needed) {
        unsigned int* partial = (unsigned int*)d_ws;
        conf_hist_partial<<<nblocks, 256, 0, stream>>>(
            yp, y, partial, n_per_batch, blocks_per_batch);
        conf_reduce<<<B, 512, 0, stream>>>(partial, out, blocks_per_batch);
    } else {
        zero_out_kernel<<<(out_size + 255) / 256, 256, 0, stream>>>(out, out_size);
        conf_hist_atomic<<<nblocks, 256, 0, stream>>>(
            yp, y, out, n_per_batch, blocks_per_batch);
    }
}

// Round 3
// 52.088 us; speedup vs baseline: 1.5206x; 1.5206x over previous
//
#include <hip/hip_runtime.h>

constexpr int C    = 21;
constexpr int CC   = C * C;   // 441 bins per batch
constexpr int NSUB = 8;       // one sub-histogram per half-wave (256 thr = 8 half-waves)

__global__ __launch_bounds__(256, 8)
void conf_hist(const int* __restrict__ yp,
               const int* __restrict__ y,
               float* __restrict__ out,
               int n_per_batch,
               int blocks_per_batch) {
    __shared__ unsigned int hist[NSUB][CC];   // 14112 B

    const int tid = threadIdx.x;
    for (int i = tid; i < NSUB * CC; i += 256)
        ((unsigned int*)hist)[i] = 0u;
    __syncthreads();

    const int b   = blockIdx.x / blocks_per_batch;
    const int blk = blockIdx.x - b * blocks_per_batch;

    const int4* yp4 = (const int4*)(yp + (size_t)b * n_per_batch);
    const int4* y4  = (const int4*)(y  + (size_t)b * n_per_batch);
    const int n4     = n_per_batch >> 2;
    const int stride = blocks_per_batch * 256;

    unsigned int* h = hist[tid >> 5];   // private per half-wave

    int i = blk * 256 + tid;

    // main loop: 8 int4 loads in flight, then 16 LDS atomics.
    // (inputs divide exactly: 4.19M/4 / (256*256) = 16 groups/thread -> 4 iters)
    for (; i + 3 * stride < n4; i += 4 * stride) {
        int4 a0 = yp4[i];
        int4 a1 = yp4[i + stride];
        int4 a2 = yp4[i + 2 * stride];
        int4 a3 = yp4[i + 3 * stride];
        int4 c0 = y4[i];
        int4 c1 = y4[i + stride];
        int4 c2 = y4[i + 2 * stride];
        int4 c3 = y4[i + 3 * stride];

        atomicAdd(&h[a0.x * C + c0.x], 1u);
        atomicAdd(&h[a0.y * C + c0.y], 1u);
        atomicAdd(&h[a0.z * C + c0.z], 1u);
        atomicAdd(&h[a0.w * C + c0.w], 1u);
        atomicAdd(&h[a1.x * C + c1.x], 1u);
        atomicAdd(&h[a1.y * C + c1.y], 1u);
        atomicAdd(&h[a1.z * C + c1.z], 1u);
        atomicAdd(&h[a1.w * C + c1.w], 1u);
        atomicAdd(&h[a2.x * C + c2.x], 1u);
        atomicAdd(&h[a2.y * C + c2.y], 1u);
        atomicAdd(&h[a2.z * C + c2.z], 1u);
        atomicAdd(&h[a2.w * C + c2.w], 1u);
        atomicAdd(&h[a3.x * C + c3.x], 1u);
        atomicAdd(&h[a3.y * C + c3.y], 1u);
        atomicAdd(&h[a3.z * C + c3.z], 1u);
        atomicAdd(&h[a3.w * C + c3.w], 1u);
    }
    // tail (not taken for the bench shape)
    for (; i < n4; i += stride) {
        int4 a = yp4[i];
        int4 c = y4[i];
        atomicAdd(&h[a.x * C + c.x], 1u);
        atomicAdd(&h[a.y * C + c.y], 1u);
        atomicAdd(&h[a.z * C + c.z], 1u);
        atomicAdd(&h[a.w * C + c.w], 1u);
    }
    __syncthreads();

    // merge: one float atomic per bin per block (overlaps across 2048 blocks)
    float* ob = out + (size_t)b * CC;
    for (int j = tid; j < CC; j += 256) {
        unsigned int s = 0;
        #pragma unroll
        for (int k = 0; k < NSUB; ++k) s += hist[k][j];
        if (s) atomicAdd(&ob[j], (float)s);
    }
}

extern "C" void kernel_launch(void* const* d_in, const int* in_sizes, int n_in,
                              void* d_out, int out_size, void* d_ws, size_t ws_size,
                              hipStream_t stream) {
    const int* yp = (const int*)d_in[0];
    const int* y  = (const int*)d_in[1];
    float* out    = (float*)d_out;

    const int total = in_sizes[0];          // B*H*W = 33,554,432
    const int B = out_size / CC;            // 8
    const int n_per_batch = total / B;      // 4,194,304

    // zero the (0xAA-poisoned) output; memset node is graph-capture safe
    hipMemsetAsync(out, 0, (size_t)out_size * sizeof(float), stream);

    const int blocks_per_batch = 256;       // 2048 blocks total, 8/CU
    conf_hist<<<B * blocks_per_batch, 256, 0, stream>>>(
        yp, y, out, n_per_batch, blocks_per_batch);
}

// Round 4
// 52.068 us; speedup vs baseline: 1.5212x; 1.0004x over previous
//
#include <hip/hip_runtime.h>

constexpr int C    = 21;
constexpr int CC   = C * C;   // 441 bins per batch
constexpr int NSUB = 8;       // one sub-histogram per half-wave

__global__ __launch_bounds__(256, 8)
void conf_hist(const int* __restrict__ yp,
               const int* __restrict__ y,
               float* __restrict__ out,
               int n_per_batch,
               int blocks_per_batch) {
    __shared__ unsigned int hist[NSUB][CC];   // 3528 words = 882 uint4 exactly

    const int tid = threadIdx.x;
    for (int i = tid; i < (NSUB * CC) / 4; i += 256)
        ((uint4*)hist)[i] = make_uint4(0u, 0u, 0u, 0u);
    __syncthreads();

    const int b   = blockIdx.x / blocks_per_batch;
    const int blk = blockIdx.x - b * blocks_per_batch;

    const int4* yp4 = (const int4*)(yp + (size_t)b * n_per_batch);
    const int4* y4  = (const int4*)(y  + (size_t)b * n_per_batch);
    const int n4     = n_per_batch >> 2;
    const int stride = blocks_per_batch * 256;

    unsigned int* h = hist[tid >> 5];

    int i = blk * 256 + tid;

    // main loop: force all 8 loads to issue before the atomic cluster.
    // sched_barrier(0) forbids the compiler from sinking loads to their uses
    // (round-3 VGPR=20 proved it was doing exactly that -> MLP of ~2).
    for (; i + 3 * stride < n4; i += 4 * stride) {
        int4 a0 = yp4[i];
        int4 a1 = yp4[i + stride];
        int4 a2 = yp4[i + 2 * stride];
        int4 a3 = yp4[i + 3 * stride];
        int4 c0 = y4[i];
        int4 c1 = y4[i + stride];
        int4 c2 = y4[i + 2 * stride];
        int4 c3 = y4[i + 3 * stride];
        __builtin_amdgcn_sched_barrier(0);

        atomicAdd(&h[a0.x * C + c0.x], 1u);
        atomicAdd(&h[a0.y * C + c0.y], 1u);
        atomicAdd(&h[a0.z * C + c0.z], 1u);
        atomicAdd(&h[a0.w * C + c0.w], 1u);
        atomicAdd(&h[a1.x * C + c1.x], 1u);
        atomicAdd(&h[a1.y * C + c1.y], 1u);
        atomicAdd(&h[a1.z * C + c1.z], 1u);
        atomicAdd(&h[a1.w * C + c1.w], 1u);
        atomicAdd(&h[a2.x * C + c2.x], 1u);
        atomicAdd(&h[a2.y * C + c2.y], 1u);
        atomicAdd(&h[a2.z * C + c2.z], 1u);
        atomicAdd(&h[a2.w * C + c2.w], 1u);
        atomicAdd(&h[a3.x * C + c3.x], 1u);
        atomicAdd(&h[a3.y * C + c3.y], 1u);
        atomicAdd(&h[a3.z * C + c3.z], 1u);
        atomicAdd(&h[a3.w * C + c3.w], 1u);
    }
    // tail (not taken for the bench shape)
    for (; i < n4; i += stride) {
        int4 a = yp4[i];
        int4 c = y4[i];
        atomicAdd(&h[a.x * C + c.x], 1u);
        atomicAdd(&h[a.y * C + c.y], 1u);
        atomicAdd(&h[a.z * C + c.z], 1u);
        atomicAdd(&h[a.w * C + c.w], 1u);
    }
    __syncthreads();

    // merge: one float atomic per bin per block
    float* ob = out + (size_t)b * CC;
    for (int j = tid; j < CC; j += 256) {
        unsigned int s = 0;
        #pragma unroll
        for (int k = 0; k < NSUB; ++k) s += hist[k][j];
        if (s) atomicAdd(&ob[j], (float)s);
    }
}

extern "C" void kernel_launch(void* const* d_in, const int* in_sizes, int n_in,
                              void* d_out, int out_size, void* d_ws, size_t ws_size,
                              hipStream_t stream) {
    const int* yp = (const int*)d_in[0];
    const int* y  = (const int*)d_in[1];
    float* out    = (float*)d_out;

    const int total = in_sizes[0];          // B*H*W = 33,554,432
    const int B = out_size / CC;            // 8
    const int n_per_batch = total / B;      // 4,194,304

    hipMemsetAsync(out, 0, (size_t)out_size * sizeof(float), stream);

    const int blocks_per_batch = 256;       // 2048 blocks total, 8/CU
    conf_hist<<<B * blocks_per_batch, 256, 0, stream>>>(
        yp, y, out, n_per_batch, blocks_per_batch);
}

// Round 5
// 48.736 us; speedup vs baseline: 1.6252x; 1.0684x over previous
//
#include <hip/hip_runtime.h>

constexpr int C    = 21;
constexpr int CC   = C * C;    // 441 bins
constexpr int CCP  = 448;      // padded partial row (multiple of 64)
constexpr int NSUB = 8;        // sub-histogram per half-wave

// ---------- stage A: per-block partial histograms, plain coalesced stores ----------
__global__ __launch_bounds__(256, 8)
void conf_hist_partial(const int* __restrict__ yp,
                       const int* __restrict__ y,
                       unsigned int* __restrict__ partial,   // [nblocks][CCP]
                       int n_per_batch,
                       int blocks_per_batch) {
    __shared__ unsigned int hist[NSUB][CC];   // 3528 words = 882 uint4

    const int tid = threadIdx.x;
    for (int i = tid; i < (NSUB * CC) / 4; i += 256)
        ((uint4*)hist)[i] = make_uint4(0u, 0u, 0u, 0u);
    __syncthreads();

    const int b   = blockIdx.x / blocks_per_batch;
    const int blk = blockIdx.x - b * blocks_per_batch;

    const int4* yp4 = (const int4*)(yp + (size_t)b * n_per_batch);
    const int4* y4  = (const int4*)(y  + (size_t)b * n_per_batch);
    const int n4     = n_per_batch >> 2;
    const int stride = blocks_per_batch * 256;

    unsigned int* h = hist[tid >> 5];

    int i = blk * 256 + tid;
    for (; i + 3 * stride < n4; i += 4 * stride) {
        int4 a0 = yp4[i];
        int4 a1 = yp4[i + stride];
        int4 a2 = yp4[i + 2 * stride];
        int4 a3 = yp4[i + 3 * stride];
        int4 c0 = y4[i];
        int4 c1 = y4[i + stride];
        int4 c2 = y4[i + 2 * stride];
        int4 c3 = y4[i + 3 * stride];

        atomicAdd(&h[a0.x * C + c0.x], 1u);
        atomicAdd(&h[a0.y * C + c0.y], 1u);
        atomicAdd(&h[a0.z * C + c0.z], 1u);
        atomicAdd(&h[a0.w * C + c0.w], 1u);
        atomicAdd(&h[a1.x * C + c1.x], 1u);
        atomicAdd(&h[a1.y * C + c1.y], 1u);
        atomicAdd(&h[a1.z * C + c1.z], 1u);
        atomicAdd(&h[a1.w * C + c1.w], 1u);
        atomicAdd(&h[a2.x * C + c2.x], 1u);
        atomicAdd(&h[a2.y * C + c2.y], 1u);
        atomicAdd(&h[a2.z * C + c2.z], 1u);
        atomicAdd(&h[a2.w * C + c2.w], 1u);
        atomicAdd(&h[a3.x * C + c3.x], 1u);
        atomicAdd(&h[a3.y * C + c3.y], 1u);
        atomicAdd(&h[a3.z * C + c3.z], 1u);
        atomicAdd(&h[a3.w * C + c3.w], 1u);
    }
    for (; i < n4; i += stride) {
        int4 a = yp4[i];
        int4 c = y4[i];
        atomicAdd(&h[a.x * C + c.x], 1u);
        atomicAdd(&h[a.y * C + c.y], 1u);
        atomicAdd(&h[a.z * C + c.z], 1u);
        atomicAdd(&h[a.w * C + c.w], 1u);
    }
    __syncthreads();

    // plain coalesced store of this block's 441 counts (no global atomics)
    unsigned int* pb = partial + (size_t)blockIdx.x * CCP;
    for (int j = tid; j < CC; j += 256) {
        unsigned int s = 0;
        #pragma unroll
        for (int k = 0; k < NSUB; ++k) s += hist[k][j];
        pb[j] = s;
    }
}

// ---------- stage B: parallel tiled reduce; fully overwrites out ----------
// grid = B * 7 blocks (7 groups of 64 bins cover 441), 256 threads.
__global__ __launch_bounds__(256)
void conf_finalize(const unsigned int* __restrict__ partial,
                   float* __restrict__ out,
                   int blocks_per_batch) {
    const int b    = blockIdx.x / 7;
    const int g    = blockIdx.x % 7;
    const int lane = threadIdx.x & 63;
    const int row0 = threadIdx.x >> 6;     // 0..3
    const int bin  = g * 64 + lane;

    const unsigned int* p = partial + (size_t)b * blocks_per_batch * CCP + bin;
    unsigned int acc = 0;
    #pragma unroll 8
    for (int r = row0; r < blocks_per_batch; r += 4)
        acc += p[(size_t)r * CCP];         // 64 consecutive bins per wave: coalesced

    __shared__ unsigned int sm[4][64];
    sm[row0][lane] = acc;
    __syncthreads();

    if (threadIdx.x < 64) {
        unsigned int s = sm[0][lane] + sm[1][lane] + sm[2][lane] + sm[3][lane];
        if (bin < CC) out[(size_t)b * CC + bin] = (float)s;
    }
}

// ---------- fallback (ws too small): atomic merge ----------
__global__ __launch_bounds__(256, 8)
void conf_hist_atomic(const int* __restrict__ yp,
                      const int* __restrict__ y,
                      float* __restrict__ out,
                      int n_per_batch,
                      int blocks_per_batch) {
    __shared__ unsigned int hist[NSUB][CC];
    const int tid = threadIdx.x;
    for (int i = tid; i < (NSUB * CC) / 4; i += 256)
        ((uint4*)hist)[i] = make_uint4(0u, 0u, 0u, 0u);
    __syncthreads();

    const int b   = blockIdx.x / blocks_per_batch;
    const int blk = blockIdx.x - b * blocks_per_batch;
    const int4* yp4 = (const int4*)(yp + (size_t)b * n_per_batch);
    const int4* y4  = (const int4*)(y  + (size_t)b * n_per_batch);
    const int n4 = n_per_batch >> 2;
    unsigned int* h = hist[tid >> 5];

    for (int i = blk * 256 + tid; i < n4; i += blocks_per_batch * 256) {
        int4 a = yp4[i];
        int4 c = y4[i];
        atomicAdd(&h[a.x * C + c.x], 1u);
        atomicAdd(&h[a.y * C + c.y], 1u);
        atomicAdd(&h[a.z * C + c.z], 1u);
        atomicAdd(&h[a.w * C + c.w], 1u);
    }
    __syncthreads();

    float* ob = out + (size_t)b * CC;
    for (int j = tid; j < CC; j += 256) {
        unsigned int s = 0;
        #pragma unroll
        for (int k = 0; k < NSUB; ++k) s += hist[k][j];
        if (s) atomicAdd(&ob[j], (float)s);
    }
}

extern "C" void kernel_launch(void* const* d_in, const int* in_sizes, int n_in,
                              void* d_out, int out_size, void* d_ws, size_t ws_size,
                              hipStream_t stream) {
    const int* yp = (const int*)d_in[0];
    const int* y  = (const int*)d_in[1];
    float* out    = (float*)d_out;

    const int total = in_sizes[0];          // B*H*W = 33,554,432
    const int B = out_size / CC;            // 8
    const int n_per_batch = total / B;      // 4,194,304

    const int blocks_per_batch = 256;       // 2048 blocks total, 8/CU
    const int nblocks = B * blocks_per_batch;
    const size_t ws_needed = (size_t)nblocks * CCP * sizeof(unsigned int); // ~3.67 MB

    if (ws_size >= ws_needed) {
        unsigned int* partial = (unsigned int*)d_ws;
        conf_hist_partial<<<nblocks, 256, 0, stream>>>(
            yp, y, partial, n_per_batch, blocks_per_batch);
        conf_finalize<<<B * 7, 256, 0, stream>>>(partial, out, blocks_per_batch);
    } else {
        hipMemsetAsync(out, 0, (size_t)out_size * sizeof(float), stream);
        conf_hist_atomic<<<nblocks, 256, 0, stream>>>(
            yp, y, out, n_per_batch, blocks_per_batch);
    }
}

// Round 6
// 47.533 us; speedup vs baseline: 1.6664x; 1.0253x over previous
//
#include <hip/hip_runtime.h>

constexpr int C    = 21;
constexpr int CC   = C * C;    // 441 bins
constexpr int CCP  = 448;      // padded partial row (multiple of 64)
constexpr int NSUB = 16;       // sub-histogram per half-wave (512 thr = 16 half-waves)
constexpr int BLK  = 512;

// ---------- stage A: per-block partial histograms ----------
__global__ __launch_bounds__(BLK, 4)
void conf_hist_partial(const int* __restrict__ yp,
                       const int* __restrict__ y,
                       unsigned int* __restrict__ partial,   // [nblocks][CCP]
                       int n_per_batch,
                       int blocks_per_batch) {
    __shared__ unsigned int hist[NSUB][CC];   // 7056 words = 1764 uint4 (28 KiB)

    const int tid = threadIdx.x;
    for (int i = tid; i < (NSUB * CC) / 4; i += BLK)
        ((uint4*)hist)[i] = make_uint4(0u, 0u, 0u, 0u);
    __syncthreads();

    const int b   = blockIdx.x / blocks_per_batch;
    const int blk = blockIdx.x - b * blocks_per_batch;

    const int4* yp4 = (const int4*)(yp + (size_t)b * n_per_batch);
    const int4* y4  = (const int4*)(y  + (size_t)b * n_per_batch);
    const int n4     = n_per_batch >> 2;
    const int stride = blocks_per_batch * BLK;

    unsigned int* h = hist[tid >> 5];   // private per half-wave

    int i = blk * BLK + tid;
    for (; i + 3 * stride < n4; i += 4 * stride) {
        int4 a0 = yp4[i];
        int4 a1 = yp4[i + stride];
        int4 a2 = yp4[i + 2 * stride];
        int4 a3 = yp4[i + 3 * stride];
        int4 c0 = y4[i];
        int4 c1 = y4[i + stride];
        int4 c2 = y4[i + 2 * stride];
        int4 c3 = y4[i + 3 * stride];

        atomicAdd(&h[a0.x * C + c0.x], 1u);
        atomicAdd(&h[a0.y * C + c0.y], 1u);
        atomicAdd(&h[a0.z * C + c0.z], 1u);
        atomicAdd(&h[a0.w * C + c0.w], 1u);
        atomicAdd(&h[a1.x * C + c1.x], 1u);
        atomicAdd(&h[a1.y * C + c1.y], 1u);
        atomicAdd(&h[a1.z * C + c1.z], 1u);
        atomicAdd(&h[a1.w * C + c1.w], 1u);
        atomicAdd(&h[a2.x * C + c2.x], 1u);
        atomicAdd(&h[a2.y * C + c2.y], 1u);
        atomicAdd(&h[a2.z * C + c2.z], 1u);
        atomicAdd(&h[a2.w * C + c2.w], 1u);
        atomicAdd(&h[a3.x * C + c3.x], 1u);
        atomicAdd(&h[a3.y * C + c3.y], 1u);
        atomicAdd(&h[a3.z * C + c3.z], 1u);
        atomicAdd(&h[a3.w * C + c3.w], 1u);
    }
    for (; i < n4; i += stride) {
        int4 a = yp4[i];
        int4 c = y4[i];
        atomicAdd(&h[a.x * C + c.x], 1u);
        atomicAdd(&h[a.y * C + c.y], 1u);
        atomicAdd(&h[a.z * C + c.z], 1u);
        atomicAdd(&h[a.w * C + c.w], 1u);
    }
    __syncthreads();

    // plain coalesced store of this block's 441 counts
    unsigned int* pb = partial + (size_t)blockIdx.x * CCP;
    for (int j = tid; j < CC; j += BLK) {
        unsigned int s = 0;
        #pragma unroll
        for (int k = 0; k < NSUB; ++k) s += hist[k][j];
        pb[j] = s;
    }
}

// ---------- stage B: parallel tiled reduce; fully overwrites out ----------
// grid = B * 7 blocks (7 groups of 64 bins cover 441), 256 threads.
__global__ __launch_bounds__(256)
void conf_finalize(const unsigned int* __restrict__ partial,
                   float* __restrict__ out,
                   int blocks_per_batch) {
    const int b    = blockIdx.x / 7;
    const int g    = blockIdx.x % 7;
    const int lane = threadIdx.x & 63;
    const int row0 = threadIdx.x >> 6;     // 0..3
    const int bin  = g * 64 + lane;

    const unsigned int* p = partial + (size_t)b * blocks_per_batch * CCP + bin;
    unsigned int acc = 0;
    #pragma unroll 8
    for (int r = row0; r < blocks_per_batch; r += 4)
        acc += p[(size_t)r * CCP];         // lanes read 64 consecutive bins: coalesced

    __shared__ unsigned int sm[4][64];
    sm[row0][lane] = acc;
    __syncthreads();

    if (threadIdx.x < 64) {
        unsigned int s = sm[0][lane] + sm[1][lane] + sm[2][lane] + sm[3][lane];
        if (bin < CC) out[(size_t)b * CC + bin] = (float)s;
    }
}

// ---------- fallback (ws too small): atomic merge ----------
__global__ __launch_bounds__(BLK, 4)
void conf_hist_atomic(const int* __restrict__ yp,
                      const int* __restrict__ y,
                      float* __restrict__ out,
                      int n_per_batch,
                      int blocks_per_batch) {
    __shared__ unsigned int hist[NSUB][CC];
    const int tid = threadIdx.x;
    for (int i = tid; i < (NSUB * CC) / 4; i += BLK)
        ((uint4*)hist)[i] = make_uint4(0u, 0u, 0u, 0u);
    __syncthreads();

    const int b   = blockIdx.x / blocks_per_batch;
    const int blk = blockIdx.x - b * blocks_per_batch;
    const int4* yp4 = (const int4*)(yp + (size_t)b * n_per_batch);
    const int4* y4  = (const int4*)(y  + (size_t)b * n_per_batch);
    const int n4 = n_per_batch >> 2;
    unsigned int* h = hist[tid >> 5];

    for (int i = blk * BLK + tid; i < n4; i += blocks_per_batch * BLK) {
        int4 a = yp4[i];
        int4 c = y4[i];
        atomicAdd(&h[a.x * C + c.x], 1u);
        atomicAdd(&h[a.y * C + c.y], 1u);
        atomicAdd(&h[a.z * C + c.z], 1u);
        atomicAdd(&h[a.w * C + c.w], 1u);
    }
    __syncthreads();

    float* ob = out + (size_t)b * CC;
    for (int j = tid; j < CC; j += BLK) {
        unsigned int s = 0;
        #pragma unroll
        for (int k = 0; k < NSUB; ++k) s += hist[k][j];
        if (s) atomicAdd(&ob[j], (float)s);
    }
}

extern "C" void kernel_launch(void* const* d_in, const int* in_sizes, int n_in,
                              void* d_out, int out_size, void* d_ws, size_t ws_size,
                              hipStream_t stream) {
    const int* yp = (const int*)d_in[0];
    const int* y  = (const int*)d_in[1];
    float* out    = (float*)d_out;

    const int total = in_sizes[0];          // B*H*W = 33,554,432
    const int B = out_size / CC;            // 8
    const int n_per_batch = total / B;      // 4,194,304

    const int blocks_per_batch = 128;       // 1024 blocks total, 4/CU x 8 waves
    const int nblocks = B * blocks_per_batch;
    const size_t ws_needed = (size_t)nblocks * CCP * sizeof(unsigned int); // ~1.84 MB

    if (ws_size >= ws_needed) {
        unsigned int* partial = (unsigned int*)d_ws;
        conf_hist_partial<<<nblocks, BLK, 0, stream>>>(
            yp, y, partial, n_per_batch, blocks_per_batch);
        conf_finalize<<<B * 7, 256, 0, stream>>>(partial, out, blocks_per_batch);
    } else {
        hipMemsetAsync(out, 0, (size_t)out_size * sizeof(float), stream);
        conf_hist_atomic<<<nblocks, BLK, 0, stream>>>(
            yp, y, out, n_per_batch, blocks_per_batch);
    }
}